// Round 6
// baseline (390.751 us; speedup 1.0000x reference)
//
#include <hip/hip_runtime.h>
#include <stdint.h>

typedef __attribute__((ext_vector_type(8))) short bf16x8;
typedef __attribute__((ext_vector_type(4))) float f32x4;

__device__ __forceinline__ ushort f2bf(float f) {
  uint32_t u = __builtin_bit_cast(uint32_t, f);
  u += 0x7fffu + ((u >> 16) & 1u);  // RNE
  return (ushort)(u >> 16);
}

__device__ __forceinline__ void async_copy16(const void* gsrc, void* ldst) {
  __builtin_amdgcn_global_load_lds(
      (const __attribute__((address_space(1))) void*)gsrc,
      (__attribute__((address_space(3))) void*)ldst, 16, 0, 0);
}

// ---------------- style linear: A[b,co] = c * dot(w[b,:], sW[co,:]) + sb[co]
__global__ void style_linear(const float* __restrict__ w, const float* __restrict__ sW,
                             const float* __restrict__ sb, float* __restrict__ A) {
  const int b = blockIdx.y;
  const int lane = threadIdx.x & 63, wv = threadIdx.x >> 6;
  const int co = blockIdx.x * 4 + wv;
  const float c = 0.04419417382415922f;  // 1/sqrt(512)
  const float* wr = w + b * 512;
  const float* Wr = sW + (size_t)co * 512;
  float s = 0.f;
#pragma unroll
  for (int i = 0; i < 8; ++i) {
    const int d = i * 64 + lane;
    s += wr[d] * Wr[d];
  }
#pragma unroll
  for (int off = 32; off; off >>= 1) s += __shfl_xor(s, off);
  if (lane == 0) A[b * 512 + co] = s * c + sb[co];
}

// ---------------- fused weight prep + sigma
__global__ void prep_sigma(const float* __restrict__ Wc, const float* __restrict__ A,
                           ushort* __restrict__ Wt, float* __restrict__ sig) {
  const int co = blockIdx.x;   // 512
  const int ci = threadIdx.x;  // 512
  const int lane = ci & 63, wid = ci >> 6;
  const float c = 0.014731391274719738f;  // 1/sqrt(512*9)
  const float* src = Wc + ((size_t)co * 512 + ci) * 9;
  float s = 0.f;
#pragma unroll
  for (int t = 0; t < 9; ++t) {
    float v = src[t] * c;
    Wt[(size_t)t * 262144 + co * 512 + ci] = f2bf(v);
    s += v * v;
  }
  __shared__ float red[8][8];
#pragma unroll
  for (int b = 0; b < 8; ++b) {
    float a = A[b * 512 + ci];
    float v = s * a * a;
#pragma unroll
    for (int off = 32; off; off >>= 1) v += __shfl_xor(v, off);
    if (lane == 0) red[b][wid] = v;
  }
  __syncthreads();
  if (ci < 8) {
    float t = 0.f;
#pragma unroll
    for (int wv = 0; wv < 8; ++wv) t += red[ci][wv];
    sig[ci * 512 + co] = rsqrtf(t + 1e-8f);
  }
}

// ---------------- zero borders of both padded NHWC buffers
__global__ void zero_border(uint4* __restrict__ x1, uint4* __restrict__ x2) {
  const int i = blockIdx.x * 256 + threadIdx.x;
  const int per = 16640;       // uint4 per batch
  const int tot = per * 8;     // per buffer
  if (i >= 2 * tot) return;
  uint4* base = (i < tot) ? x1 : x2;
  int t = (i < tot) ? i : i - tot;
  const int bb = t / per;
  int r = t - bb * per;
  int row, cell, q;
  if (r < 8448) {
    row = (r >= 4224) ? 65 : 0;
    int pos = (r >= 4224) ? r - 4224 : r;
    cell = pos >> 6;
    q = pos & 63;
  } else {
    int r2 = r - 8448;
    row = 1 + (r2 >> 7);
    cell = ((r2 >> 6) & 1) ? 65 : 0;
    q = r2 & 63;
  }
  base[(((size_t)bb * 66 + row) * 66 + cell) * 64 + q] = make_uint4(0u, 0u, 0u, 0u);
}

// ---------------- modulate + NCHW f32 -> padded NHWC bf16 transpose
__global__ void mod_transpose(const float* __restrict__ X, const float* __restrict__ A,
                              ushort* __restrict__ xs) {
  __shared__ float tile[128][65];
  const int h = blockIdx.x;
  const int ci0 = blockIdx.y * 128;
  const int b = blockIdx.z;
  const int tid = threadIdx.x;
  const int wcol = tid & 63;
  const int r0 = tid >> 6;
#pragma unroll 4
  for (int i = 0; i < 32; ++i) {
    const int cil = r0 + i * 4;
    const int ci = ci0 + cil;
    const size_t off = ((size_t)(b * 512 + ci) * 64 + h) * 64 + wcol;
    tile[cil][wcol] = X[off] * A[b * 512 + ci];
  }
  __syncthreads();
  const int sub = tid & 3;
  const int w = tid >> 2;
  ushort* dst = xs + (((size_t)b * 66 + (h + 1)) * 66 + (w + 1)) * 512 + ci0 + sub * 32;
#pragma unroll
  for (int g = 0; g < 4; ++g) {
    bf16x8 v;
#pragma unroll
    for (int j = 0; j < 8; ++j) v[j] = (short)f2bf(tile[sub * 32 + g * 8 + j][w]);
    *(bf16x8*)(dst + g * 8) = v;
  }
}

// ---------------- conv: 256co x 128px tile, K=32 ring-of-3, R4 phase structure.
// 72 KB LDS -> 2 blocks/CU: independent barrier groups give cross-block
// MFMA/DS overlap (m114 mechanism). Counted vmcnt (3), 1 barrier/slice.
#define WAITVM(N) asm volatile("s_waitcnt vmcnt(" #N ")" ::: "memory")

#define PHASE(S, Q, QS, WN, DOSTAGE)                                                 \
  do {                                                                               \
    WAITVM(WN);                                                                      \
    asm volatile("" ::: "memory");                                                   \
    __builtin_amdgcn_s_barrier();                                                    \
    asm volatile("" ::: "memory");                                                   \
    const char* baA = (const char*)(&smA[0][0]) + (Q) * 16384;                       \
    const char* baB = (const char*)(&smB[0][0]) + (Q) * 8192;                        \
    bf16x8 af[4], bv[4];                                                             \
    _Pragma("unroll") for (int m_ = 0; m_ < 4; ++m_)                                 \
        af[m_] = *(const bf16x8*)(baA + aro[m_]);                                    \
    _Pragma("unroll") for (int n_ = 0; n_ < 4; ++n_)                                 \
        bv[n_] = *(const bf16x8*)(baB + bro[n_]);                                    \
    if (DOSTAGE) stage((S) + 2, (QS));                                               \
    __builtin_amdgcn_sched_barrier(0);                                               \
    __builtin_amdgcn_s_setprio(1);                                                   \
    _Pragma("unroll") for (int m_ = 0; m_ < 4; ++m_)                                 \
      _Pragma("unroll") for (int n_ = 0; n_ < 4; ++n_)                               \
        acc[m_][n_] = __builtin_amdgcn_mfma_f32_16x16x32_bf16(af[m_], bv[n_],        \
                                                              acc[m_][n_], 0, 0, 0); \
    __builtin_amdgcn_s_setprio(0);                                                   \
    __builtin_amdgcn_sched_barrier(0);                                               \
  } while (0)

template <int OUT_MODE>
__global__ __launch_bounds__(512, 4) void conv3x3(
    const ushort* __restrict__ xs, const ushort* __restrict__ Wt,
    const float* __restrict__ sig, const float* __restrict__ noise,
    const float* __restrict__ scale_noise, const float* __restrict__ bias,
    const float* __restrict__ amod, void* __restrict__ outp) {
  __shared__ __align__(16) ushort smA[3][8192];  // 3-slot ring, A slice 256co x 32ci (16 KB)
  __shared__ __align__(16) ushort smB[3][4096];  // 3-slot ring, B slice 128px x 32ci (8 KB)
  const int tid = threadIdx.x, lane = tid & 63;
  const int wid = tid >> 6;
  const int wr = wid >> 1, wc = wid & 1;  // wave tile: 64co x 64px
  // XCD-locality remap: batch = id%8 (round-robin XCD), tile = id/8
  const int id = blockIdx.x;
  const int b = id & 7;
  const int tile = id >> 3;          // 0..63
  const int co0 = (tile & 1) * 256;
  const int px0 = (tile >> 1) * 128;
  const int h0 = px0 >> 6;

  // staging: dest = linear (thread t writes bytes t*16); source ci-slot pre-swizzled
  // [rule #21]: kb' = kb ^ ((row>>1)&3); row = t>>2, kb = t&3 -> XOR term (lane>>3)&3
  const int sswz = ((lane & 3) ^ ((lane >> 3) & 3)) * 8;  // ushort units
  int aoff[2], boff;
  {
    const int rowA0 = tid >> 2;
    aoff[0] = (co0 + rowA0) * 512 + sswz;
    aoff[1] = (co0 + 128 + rowA0) * 512 + sswz;
    const int rowB = tid >> 2;  // px within tile, 0..127
    const int hh = h0 + (rowB >> 6), ww = rowB & 63;
    boff = ((b * 66 + hh) * 66 + ww) * 512 + sswz;
  }
  ushort* ldsA0 = &smA[0][0] + tid * 8;
  ushort* ldsA1 = &smA[0][0] + 4096 + tid * 8;
  ushort* ldsB0 = &smB[0][0] + tid * 8;

  // fragment read byte offsets (swizzled to match: kb_read = (lane>>4) ^ ((lane>>1)&3))
  const int rdsw = ((lane >> 4) ^ ((lane >> 1) & 3)) * 16;
  int aro[4], bro[4];
#pragma unroll
  for (int m = 0; m < 4; ++m) aro[m] = (wr * 64 + m * 16 + (lane & 15)) * 64 + rdsw;
#pragma unroll
  for (int n = 0; n < 4; ++n) bro[n] = (wc * 64 + n * 16 + (lane & 15)) * 64 + rdsw;

  f32x4 acc[4][4];
#pragma unroll
  for (int m = 0; m < 4; ++m)
#pragma unroll
    for (int n = 0; n < 4; ++n) acc[m][n] = (f32x4){0.f, 0.f, 0.f, 0.f};

  auto stage = [&](int s, int q) {
    const int tap = s >> 4;
    const int ci0 = (s & 15) << 5;
    const int kh = tap / 3;
    const int kw = tap - kh * 3;
    const ushort* Wb = Wt + tap * 262144 + ci0;
    const ushort* Xb = xs + (kh * 66 + kw) * 512 + ci0;
    async_copy16(Wb + aoff[0], ldsA0 + q * 8192);
    async_copy16(Wb + aoff[1], ldsA1 + q * 8192);
    async_copy16(Xb + boff, ldsB0 + q * 4096);
  };

  // prologue: stage slices 0,1 (6 loads outstanding)
  stage(0, 0);
  stage(1, 1);

  // main: 144 K-slices (9 taps x 16 ci-chunks of 32); phases 0..140 all stage
  for (int s = 0; s < 141; s += 3) {
    PHASE(s + 0, 0, 2, 3, true);
    PHASE(s + 1, 1, 0, 3, true);
    PHASE(s + 2, 2, 1, 3, true);
  }
  PHASE(141, 0, 2, 3, true);   // stages slice 143
  PHASE(142, 1, 0, 3, false);
  PHASE(143, 2, 1, 0, false);

  // epilogue
  const float sn = scale_noise[0];
  const int colp = lane & 15;
  const int rq = (lane >> 4) * 4;
  float nz[4];
#pragma unroll
  for (int n = 0; n < 4; ++n)
    nz[n] = sn * noise[b * 4096 + px0 + wc * 64 + n * 16 + colp];
#pragma unroll
  for (int m = 0; m < 4; ++m) {
    const int cob = co0 + wr * 64 + m * 16 + rq;
    float sg[4], bs[4], am[4];
#pragma unroll
    for (int r = 0; r < 4; ++r) {
      sg[r] = sig[b * 512 + cob + r];
      bs[r] = bias[cob + r];
      am[r] = (OUT_MODE == 0) ? amod[b * 512 + cob + r] : 0.f;
    }
#pragma unroll
    for (int n = 0; n < 4; ++n) {
      const int px = px0 + wc * 64 + n * 16 + colp;
      if (OUT_MODE == 0) {
        const int hh = px >> 6, ww = px & 63;
        ushort pk[4];
#pragma unroll
        for (int r = 0; r < 4; ++r) {
          float v = acc[m][n][r] * sg[r] + nz[n] + bs[r];
          v = (v > 0.f) ? v : 0.2f * v;
          pk[r] = f2bf(v * am[r]);
        }
        uint2 u;
        u.x = (uint32_t)pk[0] | ((uint32_t)pk[1] << 16);
        u.y = (uint32_t)pk[2] | ((uint32_t)pk[3] << 16);
        *(uint2*)((ushort*)outp + (((size_t)b * 66 + hh + 1) * 66 + (ww + 1)) * 512 + cob) = u;
      } else {
#pragma unroll
        for (int r = 0; r < 4; ++r) {
          float v = acc[m][n][r] * sg[r] + nz[n] + bs[r];
          v = (v > 0.f) ? v : 0.2f * v;
          ((float*)outp)[((size_t)b * 512 + cob + r) * 4096 + px] = v;
        }
      }
    }
  }
}

// ---------------- RGB 1x1 conv (no demod)
__global__ void rgb_k(const float* __restrict__ X, const float* __restrict__ Ar,
                      const float* __restrict__ rgbW, const float* __restrict__ rgbB,
                      float* __restrict__ out) {
  __shared__ float wmod[3 * 512];
  const int b = blockIdx.y;
  const int tid = threadIdx.x;
  const float c = 0.04419417382415922f;  // 1/sqrt(512)
  for (int idx = tid; idx < 1536; idx += 256)
    wmod[idx] = rgbW[idx] * c * Ar[b * 512 + (idx & 511)];
  __syncthreads();
  const int p = blockIdx.x * 256 + tid;
  const float* xb = X + (size_t)b * 512 * 4096 + p;
  float a0 = 0.f, a1 = 0.f, a2 = 0.f;
  for (int ci = 0; ci < 512; ++ci) {
    float xv = xb[(size_t)ci * 4096];
    a0 += wmod[ci] * xv;
    a1 += wmod[512 + ci] * xv;
    a2 += wmod[1024 + ci] * xv;
  }
  float v0 = a0 + rgbB[0], v1 = a1 + rgbB[1], v2 = a2 + rgbB[2];
  v0 = (v0 > 0.f) ? v0 : 0.2f * v0;
  v1 = (v1 > 0.f) ? v1 : 0.2f * v1;
  v2 = (v2 > 0.f) ? v2 : 0.2f * v2;
  out[((size_t)b * 3 + 0) * 4096 + p] = v0;
  out[((size_t)b * 3 + 1) * 4096 + p] = v1;
  out[((size_t)b * 3 + 2) * 4096 + p] = v2;
}

extern "C" void kernel_launch(void* const* d_in, const int* in_sizes, int n_in,
                              void* d_out, int out_size, void* d_ws, size_t ws_size,
                              hipStream_t stream) {
  const float* x     = (const float*)d_in[0];
  const float* w     = (const float*)d_in[1];
  const float* noise = (const float*)d_in[2];
  const float* s1_sW = (const float*)d_in[3];
  const float* s1_sb = (const float*)d_in[4];
  const float* s1_cW = (const float*)d_in[5];
  const float* s1_sn = (const float*)d_in[6];
  const float* s1_b  = (const float*)d_in[7];
  const float* s2_sW = (const float*)d_in[8];
  const float* s2_sb = (const float*)d_in[9];
  const float* s2_cW = (const float*)d_in[10];
  const float* s2_sn = (const float*)d_in[11];
  const float* s2_b  = (const float*)d_in[12];
  const float* r_sW  = (const float*)d_in[13];
  const float* r_sb  = (const float*)d_in[14];
  const float* r_cW  = (const float*)d_in[15];
  const float* r_b   = (const float*)d_in[16];

  char* ws = (char*)d_ws;
  float*  A1  = (float*)(ws + 0);
  float*  A2  = (float*)(ws + 16384);
  float*  Arr = (float*)(ws + 32768);
  float*  sg1 = (float*)(ws + 49152);
  float*  sg2 = (float*)(ws + 65536);
  ushort* Wt1 = (ushort*)(ws + 98304);            // 4.5 MB
  ushort* xs1 = (ushort*)(ws + 4816896);          // padded NHWC, 35.7 MB
  ushort* Wt2 = (ushort*)(ws + 4816896);          // aliases xs1 (used after conv1)
  ushort* xs2 = (ushort*)(ws + 40501248);         // padded NHWC, 35.7 MB
  float* outx   = (float*)d_out;
  float* outrgb = outx + (size_t)8 * 512 * 4096;

  style_linear<<<dim3(128, 8), 256, 0, stream>>>(w, s1_sW, s1_sb, A1);
  style_linear<<<dim3(128, 8), 256, 0, stream>>>(w, s2_sW, s2_sb, A2);
  style_linear<<<dim3(128, 8), 256, 0, stream>>>(w, r_sW, r_sb, Arr);

  prep_sigma<<<512, 512, 0, stream>>>(s1_cW, A1, Wt1, sg1);

  zero_border<<<1040, 256, 0, stream>>>((uint4*)xs1, (uint4*)xs2);
  mod_transpose<<<dim3(64, 4, 8), 256, 0, stream>>>(x, A1, xs1);

  conv3x3<0><<<dim3(512), 512, 0, stream>>>(xs1, Wt1, sg1, noise, s1_sn, s1_b, A2, (void*)xs2);
  prep_sigma<<<512, 512, 0, stream>>>(s2_cW, A2, Wt2, sg2);  // Wt2 aliases xs1: after conv1
  conv3x3<1><<<dim3(512), 512, 0, stream>>>(xs2, Wt2, sg2, noise + 32768, s2_sn, s2_b, sg2,
                                            (void*)outx);
  rgb_k<<<dim3(16, 8), 256, 0, stream>>>(outx, Arr, r_cW, r_b, outrgb);
}

// Round 7
// 353.859 us; speedup vs baseline: 1.1043x; 1.1043x over previous
//
#include <hip/hip_runtime.h>
#include <stdint.h>

typedef __attribute__((ext_vector_type(8))) short bf16x8;
typedef __attribute__((ext_vector_type(4))) float f32x4;

__device__ __forceinline__ ushort f2bf(float f) {
  uint32_t u = __builtin_bit_cast(uint32_t, f);
  u += 0x7fffu + ((u >> 16) & 1u);  // RNE
  return (ushort)(u >> 16);
}

__device__ __forceinline__ void async_copy16(const void* gsrc, void* ldst) {
  __builtin_amdgcn_global_load_lds(
      (const __attribute__((address_space(1))) void*)gsrc,
      (__attribute__((address_space(3))) void*)ldst, 16, 0, 0);
}

// ---------------- style linear: A[b,co] = c * dot(w[b,:], sW[co,:]) + sb[co]
__global__ void style_linear(const float* __restrict__ w, const float* __restrict__ sW,
                             const float* __restrict__ sb, float* __restrict__ A) {
  const int b = blockIdx.y;
  const int lane = threadIdx.x & 63, wv = threadIdx.x >> 6;
  const int co = blockIdx.x * 4 + wv;
  const float c = 0.04419417382415922f;  // 1/sqrt(512)
  const float* wr = w + b * 512;
  const float* Wr = sW + (size_t)co * 512;
  float s = 0.f;
#pragma unroll
  for (int i = 0; i < 8; ++i) {
    const int d = i * 64 + lane;
    s += wr[d] * Wr[d];
  }
#pragma unroll
  for (int off = 32; off; off >>= 1) s += __shfl_xor(s, off);
  if (lane == 0) A[b * 512 + co] = s * c + sb[co];
}

// ---------------- fused weight prep + sigma
__global__ void prep_sigma(const float* __restrict__ Wc, const float* __restrict__ A,
                           ushort* __restrict__ Wt, float* __restrict__ sig) {
  const int co = blockIdx.x;   // 512
  const int ci = threadIdx.x;  // 512
  const int lane = ci & 63, wid = ci >> 6;
  const float c = 0.014731391274719738f;  // 1/sqrt(512*9)
  const float* src = Wc + ((size_t)co * 512 + ci) * 9;
  float s = 0.f;
#pragma unroll
  for (int t = 0; t < 9; ++t) {
    float v = src[t] * c;
    Wt[(size_t)t * 262144 + co * 512 + ci] = f2bf(v);
    s += v * v;
  }
  __shared__ float red[8][8];
#pragma unroll
  for (int b = 0; b < 8; ++b) {
    float a = A[b * 512 + ci];
    float v = s * a * a;
#pragma unroll
    for (int off = 32; off; off >>= 1) v += __shfl_xor(v, off);
    if (lane == 0) red[b][wid] = v;
  }
  __syncthreads();
  if (ci < 8) {
    float t = 0.f;
#pragma unroll
    for (int wv = 0; wv < 8; ++wv) t += red[ci][wv];
    sig[ci * 512 + co] = rsqrtf(t + 1e-8f);
  }
}

// ---------------- zero borders of both padded NHWC buffers
__global__ void zero_border(uint4* __restrict__ x1, uint4* __restrict__ x2) {
  const int i = blockIdx.x * 256 + threadIdx.x;
  const int per = 16640;       // uint4 per batch
  const int tot = per * 8;     // per buffer
  if (i >= 2 * tot) return;
  uint4* base = (i < tot) ? x1 : x2;
  int t = (i < tot) ? i : i - tot;
  const int bb = t / per;
  int r = t - bb * per;
  int row, cell, q;
  if (r < 8448) {
    row = (r >= 4224) ? 65 : 0;
    int pos = (r >= 4224) ? r - 4224 : r;
    cell = pos >> 6;
    q = pos & 63;
  } else {
    int r2 = r - 8448;
    row = 1 + (r2 >> 7);
    cell = ((r2 >> 6) & 1) ? 65 : 0;
    q = r2 & 63;
  }
  base[(((size_t)bb * 66 + row) * 66 + cell) * 64 + q] = make_uint4(0u, 0u, 0u, 0u);
}

// ---------------- modulate + NCHW f32 -> padded NHWC bf16 transpose
__global__ void mod_transpose(const float* __restrict__ X, const float* __restrict__ A,
                              ushort* __restrict__ xs) {
  __shared__ float tile[128][65];
  const int h = blockIdx.x;
  const int ci0 = blockIdx.y * 128;
  const int b = blockIdx.z;
  const int tid = threadIdx.x;
  const int wcol = tid & 63;
  const int r0 = tid >> 6;
#pragma unroll 4
  for (int i = 0; i < 32; ++i) {
    const int cil = r0 + i * 4;
    const int ci = ci0 + cil;
    const size_t off = ((size_t)(b * 512 + ci) * 64 + h) * 64 + wcol;
    tile[cil][wcol] = X[off] * A[b * 512 + ci];
  }
  __syncthreads();
  const int sub = tid & 3;
  const int w = tid >> 2;
  ushort* dst = xs + (((size_t)b * 66 + (h + 1)) * 66 + (w + 1)) * 512 + ci0 + sub * 32;
#pragma unroll
  for (int g = 0; g < 4; ++g) {
    bf16x8 v;
#pragma unroll
    for (int j = 0; j < 8; ++j) v[j] = (short)f2bf(tile[sub * 32 + g * 8 + j][w]);
    *(bf16x8*)(dst + g * 8) = v;
  }
}

// ---------------- conv: 256x256 tile, ring-of-4 K-slices, counted vmcnt.
// Reads interleaved af/bv + NO sched_barrier between reads and MFMAs: the
// compiler emits counted lgkmcnt per consuming MFMA, so the MFMA pipe starts
// after ~2 reads instead of after the full 12-read drain (the R4 serializer).
#define WAITVM(N) asm volatile("s_waitcnt vmcnt(" #N ")" ::: "memory")

#define PHASE(S, WN, DOSTAGE)                                                        \
  do {                                                                               \
    WAITVM(WN);                                                                      \
    asm volatile("" ::: "memory");                                                   \
    __builtin_amdgcn_s_barrier();                                                    \
    asm volatile("" ::: "memory");                                                   \
    if (DOSTAGE) stage((S) + 3);                                                     \
    const int q_ = (S) & 3;                                                          \
    const char* baA = (const char*)(&smA[0][0] + q_ * 8192);                         \
    const char* baB = (const char*)(&smB[0][0] + q_ * 8192);                         \
    bf16x8 af[8], bv[4];                                                             \
    af[0] = *(const bf16x8*)(baA + aro[0]);                                          \
    bv[0] = *(const bf16x8*)(baB + bro[0]);                                          \
    af[1] = *(const bf16x8*)(baA + aro[1]);                                          \
    bv[1] = *(const bf16x8*)(baB + bro[1]);                                          \
    af[2] = *(const bf16x8*)(baA + aro[2]);                                          \
    bv[2] = *(const bf16x8*)(baB + bro[2]);                                          \
    af[3] = *(const bf16x8*)(baA + aro[3]);                                          \
    bv[3] = *(const bf16x8*)(baB + bro[3]);                                          \
    af[4] = *(const bf16x8*)(baA + aro[4]);                                          \
    af[5] = *(const bf16x8*)(baA + aro[5]);                                          \
    af[6] = *(const bf16x8*)(baA + aro[6]);                                          \
    af[7] = *(const bf16x8*)(baA + aro[7]);                                          \
    __builtin_amdgcn_s_setprio(1);                                                   \
    _Pragma("unroll") for (int m_ = 0; m_ < 8; ++m_)                                 \
      _Pragma("unroll") for (int n_ = 0; n_ < 4; ++n_)                               \
        acc[m_][n_] = __builtin_amdgcn_mfma_f32_16x16x32_bf16(af[m_], bv[n_],        \
                                                              acc[m_][n_], 0, 0, 0); \
    __builtin_amdgcn_s_setprio(0);                                                   \
  } while (0)

template <int OUT_MODE>
__global__ __launch_bounds__(512, 2) void conv3x3(
    const ushort* __restrict__ xs, const ushort* __restrict__ Wt,
    const float* __restrict__ sig, const float* __restrict__ noise,
    const float* __restrict__ scale_noise, const float* __restrict__ bias,
    const float* __restrict__ amod, void* __restrict__ outp) {
  __shared__ __align__(16) ushort smA[4][8192];  // 4-slot ring, A slice 256co x 32ci
  __shared__ __align__(16) ushort smB[4][8192];  // 4-slot ring, B slice 256px x 32ci
  const int tid = threadIdx.x, lane = tid & 63, wid = tid >> 6;
  const int wr = wid >> 2, wc = wid & 3;
  // XCD-locality remap: batch = id%8 (round-robin XCD), tile = id/8
  const int id = blockIdx.x;
  const int b = id & 7;
  const int tile = id >> 3;  // 0..31
  const int co0 = (tile & 1) * 256;
  const int px0 = (tile >> 1) * 256;
  const int h0 = px0 >> 6;

  // staging: dest = wavebase + lane*16 (HW-linear); source ci-slot pre-swizzled [rule #21]
  const int sswz = ((lane & 3) ^ ((lane >> 3) & 3)) * 8;  // ushort units
  int aoff[2], boff[2];
  ushort *ldsA[2], *ldsB[2];
#pragma unroll
  for (int i = 0; i < 2; ++i) {
    const int row = (i * 8 + wid) * 16 + (lane >> 2);
    aoff[i] = (co0 + row) * 512 + sswz;
    const int hh = h0 + (row >> 6), ww = row & 63;
    boff[i] = ((b * 66 + hh) * 66 + ww) * 512 + sswz;
    ldsA[i] = &smA[0][0] + (i * 8 + wid) * 512 + lane * 8;
    ldsB[i] = &smB[0][0] + (i * 8 + wid) * 512 + lane * 8;
  }
  // fragment read byte offsets (swizzled to match)
  const int rdsw = ((lane >> 4) ^ ((lane >> 1) & 3)) * 16;
  int aro[8], bro[4];
#pragma unroll
  for (int m = 0; m < 8; ++m) aro[m] = (wr * 128 + m * 16 + (lane & 15)) * 64 + rdsw;
#pragma unroll
  for (int n = 0; n < 4; ++n) bro[n] = (wc * 64 + n * 16 + (lane & 15)) * 64 + rdsw;

  f32x4 acc[8][4];
#pragma unroll
  for (int m = 0; m < 8; ++m)
#pragma unroll
    for (int n = 0; n < 4; ++n) acc[m][n] = (f32x4){0.f, 0.f, 0.f, 0.f};

  auto stage = [&](int s) {
    const int tap = s >> 4;
    const int ci0 = (s & 15) << 5;
    const int kh = tap / 3;
    const int kw = tap - kh * 3;
    const int q = s & 3;
    const ushort* Wb = Wt + tap * 262144 + ci0;
    const ushort* Xb = xs + (kh * 66 + kw) * 512 + ci0;
    async_copy16(Wb + aoff[0], ldsA[0] + q * 8192);
    async_copy16(Wb + aoff[1], ldsA[1] + q * 8192);
    async_copy16(Xb + boff[0], ldsB[0] + q * 8192);
    async_copy16(Xb + boff[1], ldsB[1] + q * 8192);
  };

  // prologue: stage ring slots 0..2 (12 loads outstanding)
  stage(0);
  stage(1);
  stage(2);

  // main: 144 K-slices (9 taps x 16 ci-chunks of 32)
  for (int s = 0; s < 140; s += 4) {
    PHASE(s + 0, 8, true);
    PHASE(s + 1, 8, true);
    PHASE(s + 2, 8, true);
    PHASE(s + 3, 8, true);
  }
  PHASE(140, 8, true);   // stages slice 143
  PHASE(141, 8, false);
  PHASE(142, 4, false);
  PHASE(143, 0, false);

  // epilogue
  const float sn = scale_noise[0];
  const int colp = lane & 15;
  const int rq = (lane >> 4) * 4;
  float nz[4];
#pragma unroll
  for (int n = 0; n < 4; ++n)
    nz[n] = sn * noise[b * 4096 + px0 + wc * 64 + n * 16 + colp];
#pragma unroll
  for (int m = 0; m < 8; ++m) {
    const int cob = co0 + wr * 128 + m * 16 + rq;
    float sg[4], bs[4], am[4];
#pragma unroll
    for (int r = 0; r < 4; ++r) {
      sg[r] = sig[b * 512 + cob + r];
      bs[r] = bias[cob + r];
      am[r] = (OUT_MODE == 0) ? amod[b * 512 + cob + r] : 0.f;
    }
#pragma unroll
    for (int n = 0; n < 4; ++n) {
      const int px = px0 + wc * 64 + n * 16 + colp;
      if (OUT_MODE == 0) {
        const int hh = px >> 6, ww = px & 63;
        ushort pk[4];
#pragma unroll
        for (int r = 0; r < 4; ++r) {
          float v = acc[m][n][r] * sg[r] + nz[n] + bs[r];
          v = (v > 0.f) ? v : 0.2f * v;
          pk[r] = f2bf(v * am[r]);
        }
        uint2 u;
        u.x = (uint32_t)pk[0] | ((uint32_t)pk[1] << 16);
        u.y = (uint32_t)pk[2] | ((uint32_t)pk[3] << 16);
        *(uint2*)((ushort*)outp + (((size_t)b * 66 + hh + 1) * 66 + (ww + 1)) * 512 + cob) = u;
      } else {
#pragma unroll
        for (int r = 0; r < 4; ++r) {
          float v = acc[m][n][r] * sg[r] + nz[n] + bs[r];
          v = (v > 0.f) ? v : 0.2f * v;
          ((float*)outp)[((size_t)b * 512 + cob + r) * 4096 + px] = v;
        }
      }
    }
  }
}

// ---------------- RGB 1x1 conv (no demod)
__global__ void rgb_k(const float* __restrict__ X, const float* __restrict__ Ar,
                      const float* __restrict__ rgbW, const float* __restrict__ rgbB,
                      float* __restrict__ out) {
  __shared__ float wmod[3 * 512];
  const int b = blockIdx.y;
  const int tid = threadIdx.x;
  const float c = 0.04419417382415922f;  // 1/sqrt(512)
  for (int idx = tid; idx < 1536; idx += 256)
    wmod[idx] = rgbW[idx] * c * Ar[b * 512 + (idx & 511)];
  __syncthreads();
  const int p = blockIdx.x * 256 + tid;
  const float* xb = X + (size_t)b * 512 * 4096 + p;
  float a0 = 0.f, a1 = 0.f, a2 = 0.f;
  for (int ci = 0; ci < 512; ++ci) {
    float xv = xb[(size_t)ci * 4096];
    a0 += wmod[ci] * xv;
    a1 += wmod[512 + ci] * xv;
    a2 += wmod[1024 + ci] * xv;
  }
  float v0 = a0 + rgbB[0], v1 = a1 + rgbB[1], v2 = a2 + rgbB[2];
  v0 = (v0 > 0.f) ? v0 : 0.2f * v0;
  v1 = (v1 > 0.f) ? v1 : 0.2f * v1;
  v2 = (v2 > 0.f) ? v2 : 0.2f * v2;
  out[((size_t)b * 3 + 0) * 4096 + p] = v0;
  out[((size_t)b * 3 + 1) * 4096 + p] = v1;
  out[((size_t)b * 3 + 2) * 4096 + p] = v2;
}

extern "C" void kernel_launch(void* const* d_in, const int* in_sizes, int n_in,
                              void* d_out, int out_size, void* d_ws, size_t ws_size,
                              hipStream_t stream) {
  const float* x     = (const float*)d_in[0];
  const float* w     = (const float*)d_in[1];
  const float* noise = (const float*)d_in[2];
  const float* s1_sW = (const float*)d_in[3];
  const float* s1_sb = (const float*)d_in[4];
  const float* s1_cW = (const float*)d_in[5];
  const float* s1_sn = (const float*)d_in[6];
  const float* s1_b  = (const float*)d_in[7];
  const float* s2_sW = (const float*)d_in[8];
  const float* s2_sb = (const float*)d_in[9];
  const float* s2_cW = (const float*)d_in[10];
  const float* s2_sn = (const float*)d_in[11];
  const float* s2_b  = (const float*)d_in[12];
  const float* r_sW  = (const float*)d_in[13];
  const float* r_sb  = (const float*)d_in[14];
  const float* r_cW  = (const float*)d_in[15];
  const float* r_b   = (const float*)d_in[16];

  char* ws = (char*)d_ws;
  float*  A1  = (float*)(ws + 0);
  float*  A2  = (float*)(ws + 16384);
  float*  Arr = (float*)(ws + 32768);
  float*  sg1 = (float*)(ws + 49152);
  float*  sg2 = (float*)(ws + 65536);
  ushort* Wt1 = (ushort*)(ws + 98304);            // 4.5 MB
  ushort* xs1 = (ushort*)(ws + 4816896);          // padded NHWC, 35.7 MB
  ushort* Wt2 = (ushort*)(ws + 4816896);          // aliases xs1 (used after conv1)
  ushort* xs2 = (ushort*)(ws + 40501248);         // padded NHWC, 35.7 MB
  float* outx   = (float*)d_out;
  float* outrgb = outx + (size_t)8 * 512 * 4096;

  style_linear<<<dim3(128, 8), 256, 0, stream>>>(w, s1_sW, s1_sb, A1);
  style_linear<<<dim3(128, 8), 256, 0, stream>>>(w, s2_sW, s2_sb, A2);
  style_linear<<<dim3(128, 8), 256, 0, stream>>>(w, r_sW, r_sb, Arr);

  prep_sigma<<<512, 512, 0, stream>>>(s1_cW, A1, Wt1, sg1);

  zero_border<<<1040, 256, 0, stream>>>((uint4*)xs1, (uint4*)xs2);
  mod_transpose<<<dim3(64, 4, 8), 256, 0, stream>>>(x, A1, xs1);

  conv3x3<0><<<dim3(256), 512, 0, stream>>>(xs1, Wt1, sg1, noise, s1_sn, s1_b, A2, (void*)xs2);
  prep_sigma<<<512, 512, 0, stream>>>(s2_cW, A2, Wt2, sg2);  // Wt2 aliases xs1: after conv1
  conv3x3<1><<<dim3(256), 512, 0, stream>>>(xs2, Wt2, sg2, noise + 32768, s2_sn, s2_b, sg2,
                                            (void*)outx);
  rgb_k<<<dim3(16, 8), 256, 0, stream>>>(outx, Arr, r_cW, r_b, outrgb);
}

// Round 8
// 339.972 us; speedup vs baseline: 1.1494x; 1.0408x over previous
//
#include <hip/hip_runtime.h>
#include <stdint.h>

typedef __attribute__((ext_vector_type(8))) short bf16x8;
typedef __attribute__((ext_vector_type(4))) float f32x4;

__device__ __forceinline__ ushort f2bf(float f) {
  uint32_t u = __builtin_bit_cast(uint32_t, f);
  u += 0x7fffu + ((u >> 16) & 1u);  // RNE
  return (ushort)(u >> 16);
}

__device__ __forceinline__ void async_copy16(const void* gsrc, void* ldst) {
  __builtin_amdgcn_global_load_lds(
      (const __attribute__((address_space(1))) void*)gsrc,
      (__attribute__((address_space(3))) void*)ldst, 16, 0, 0);
}

// ---------------- style linear: A[b,co] = c * dot(w[b,:], sW[co,:]) + sb[co]
__global__ void style_linear(const float* __restrict__ w, const float* __restrict__ sW,
                             const float* __restrict__ sb, float* __restrict__ A) {
  const int b = blockIdx.y;
  const int lane = threadIdx.x & 63, wv = threadIdx.x >> 6;
  const int co = blockIdx.x * 4 + wv;
  const float c = 0.04419417382415922f;  // 1/sqrt(512)
  const float* wr = w + b * 512;
  const float* Wr = sW + (size_t)co * 512;
  float s = 0.f;
#pragma unroll
  for (int i = 0; i < 8; ++i) {
    const int d = i * 64 + lane;
    s += wr[d] * Wr[d];
  }
#pragma unroll
  for (int off = 32; off; off >>= 1) s += __shfl_xor(s, off);
  if (lane == 0) A[b * 512 + co] = s * c + sb[co];
}

// ---------------- fused weight prep + sigma
__global__ void prep_sigma(const float* __restrict__ Wc, const float* __restrict__ A,
                           ushort* __restrict__ Wt, float* __restrict__ sig) {
  const int co = blockIdx.x;   // 512
  const int ci = threadIdx.x;  // 512
  const int lane = ci & 63, wid = ci >> 6;
  const float c = 0.014731391274719738f;  // 1/sqrt(512*9)
  const float* src = Wc + ((size_t)co * 512 + ci) * 9;
  float s = 0.f;
#pragma unroll
  for (int t = 0; t < 9; ++t) {
    float v = src[t] * c;
    Wt[(size_t)t * 262144 + co * 512 + ci] = f2bf(v);
    s += v * v;
  }
  __shared__ float red[8][8];
#pragma unroll
  for (int b = 0; b < 8; ++b) {
    float a = A[b * 512 + ci];
    float v = s * a * a;
#pragma unroll
    for (int off = 32; off; off >>= 1) v += __shfl_xor(v, off);
    if (lane == 0) red[b][wid] = v;
  }
  __syncthreads();
  if (ci < 8) {
    float t = 0.f;
#pragma unroll
    for (int wv = 0; wv < 8; ++wv) t += red[ci][wv];
    sig[ci * 512 + co] = rsqrtf(t + 1e-8f);
  }
}

// ---------------- zero borders of both padded NHWC buffers
__global__ void zero_border(uint4* __restrict__ x1, uint4* __restrict__ x2) {
  const int i = blockIdx.x * 256 + threadIdx.x;
  const int per = 16640;       // uint4 per batch
  const int tot = per * 8;     // per buffer
  if (i >= 2 * tot) return;
  uint4* base = (i < tot) ? x1 : x2;
  int t = (i < tot) ? i : i - tot;
  const int bb = t / per;
  int r = t - bb * per;
  int row, cell, q;
  if (r < 8448) {
    row = (r >= 4224) ? 65 : 0;
    int pos = (r >= 4224) ? r - 4224 : r;
    cell = pos >> 6;
    q = pos & 63;
  } else {
    int r2 = r - 8448;
    row = 1 + (r2 >> 7);
    cell = ((r2 >> 6) & 1) ? 65 : 0;
    q = r2 & 63;
  }
  base[(((size_t)bb * 66 + row) * 66 + cell) * 64 + q] = make_uint4(0u, 0u, 0u, 0u);
}

// ---------------- modulate + NCHW f32 -> padded NHWC bf16 transpose
__global__ void mod_transpose(const float* __restrict__ X, const float* __restrict__ A,
                              ushort* __restrict__ xs) {
  __shared__ float tile[128][65];
  const int h = blockIdx.x;
  const int ci0 = blockIdx.y * 128;
  const int b = blockIdx.z;
  const int tid = threadIdx.x;
  const int wcol = tid & 63;
  const int r0 = tid >> 6;
#pragma unroll 4
  for (int i = 0; i < 32; ++i) {
    const int cil = r0 + i * 4;
    const int ci = ci0 + cil;
    const size_t off = ((size_t)(b * 512 + ci) * 64 + h) * 64 + wcol;
    tile[cil][wcol] = X[off] * A[b * 512 + ci];
  }
  __syncthreads();
  const int sub = tid & 3;
  const int w = tid >> 2;
  ushort* dst = xs + (((size_t)b * 66 + (h + 1)) * 66 + (w + 1)) * 512 + ci0 + sub * 32;
#pragma unroll
  for (int g = 0; g < 4; ++g) {
    bf16x8 v;
#pragma unroll
    for (int j = 0; j < 8; ++j) v[j] = (short)f2bf(tile[sub * 32 + g * 8 + j][w]);
    *(bf16x8*)(dst + g * 8) = v;
  }
}

// ---------------- conv: 256x256 tile, ring-of-4 K-slices, FULL-SLICE READ-AHEAD.
// Phase p: barrier -> ds_read frags of slice p+1 (slot staged 2 phases ago) ->
// stage(p+3) -> MFMA slice p on frags read LAST phase (lgkm already satisfied).
// The 1408-cyc DS drain of slice p+1 runs under the 1242-cyc MFMA shadow of p.
#define WAITVM(N) asm volatile("s_waitcnt vmcnt(" #N ")" ::: "memory")

#define READS(S, AF, BV)                                                     \
  do {                                                                       \
    const int q_ = (S) & 3;                                                  \
    const char* baA = (const char*)(&smA[0][0] + q_ * 8192);                 \
    const char* baB = (const char*)(&smB[0][0] + q_ * 8192);                 \
    _Pragma("unroll") for (int m_ = 0; m_ < 8; ++m_)                         \
        AF[m_] = *(const bf16x8*)(baA + aro[m_]);                            \
    _Pragma("unroll") for (int n_ = 0; n_ < 4; ++n_)                         \
        BV[n_] = *(const bf16x8*)(baB + bro[n_]);                            \
  } while (0)

// PH(phase S): MFMA slice S from (MAF,MBV); read slice S+1 into (RAF,RBV)
#define PH(S, WN, DOREAD, DOSTAGE, RAF, RBV, MAF, MBV)                               \
  do {                                                                               \
    WAITVM(WN);                                                                      \
    asm volatile("" ::: "memory");                                                   \
    __builtin_amdgcn_s_barrier();                                                    \
    asm volatile("" ::: "memory");                                                   \
    if (DOREAD) READS((S) + 1, RAF, RBV);                                            \
    if (DOSTAGE) stage((S) + 3);                                                     \
    __builtin_amdgcn_sched_barrier(0);                                               \
    __builtin_amdgcn_s_setprio(1);                                                   \
    _Pragma("unroll") for (int m_ = 0; m_ < 8; ++m_)                                 \
      _Pragma("unroll") for (int n_ = 0; n_ < 4; ++n_)                               \
        acc[m_][n_] = __builtin_amdgcn_mfma_f32_16x16x32_bf16(MAF[m_], MBV[n_],      \
                                                              acc[m_][n_], 0, 0, 0); \
    __builtin_amdgcn_s_setprio(0);                                                   \
    __builtin_amdgcn_sched_barrier(0);                                               \
  } while (0)

template <int OUT_MODE>
__global__ __launch_bounds__(512, 2) void conv3x3(
    const ushort* __restrict__ xs, const ushort* __restrict__ Wt,
    const float* __restrict__ sig, const float* __restrict__ noise,
    const float* __restrict__ scale_noise, const float* __restrict__ bias,
    const float* __restrict__ amod, void* __restrict__ outp) {
  __shared__ __align__(16) ushort smA[4][8192];  // 4-slot ring, A slice 256co x 32ci
  __shared__ __align__(16) ushort smB[4][8192];  // 4-slot ring, B slice 256px x 32ci
  const int tid = threadIdx.x, lane = tid & 63, wid = tid >> 6;
  const int wr = wid >> 2, wc = wid & 3;
  // XCD-locality remap: batch = id%8 (round-robin XCD), tile = id/8
  const int id = blockIdx.x;
  const int b = id & 7;
  const int tile = id >> 3;  // 0..31
  const int co0 = (tile & 1) * 256;
  const int px0 = (tile >> 1) * 256;
  const int h0 = px0 >> 6;

  // staging: dest = wavebase + lane*16 (HW-linear); source ci-slot pre-swizzled [rule #21]
  const int sswz = ((lane & 3) ^ ((lane >> 3) & 3)) * 8;  // ushort units
  int aoff[2], boff[2];
  ushort *ldsA[2], *ldsB[2];
#pragma unroll
  for (int i = 0; i < 2; ++i) {
    const int row = (i * 8 + wid) * 16 + (lane >> 2);
    aoff[i] = (co0 + row) * 512 + sswz;
    const int hh = h0 + (row >> 6), ww = row & 63;
    boff[i] = ((b * 66 + hh) * 66 + ww) * 512 + sswz;
    ldsA[i] = &smA[0][0] + (i * 8 + wid) * 512 + lane * 8;
    ldsB[i] = &smB[0][0] + (i * 8 + wid) * 512 + lane * 8;
  }
  // fragment read byte offsets (swizzled to match)
  const int rdsw = ((lane >> 4) ^ ((lane >> 1) & 3)) * 16;
  int aro[8], bro[4];
#pragma unroll
  for (int m = 0; m < 8; ++m) aro[m] = (wr * 128 + m * 16 + (lane & 15)) * 64 + rdsw;
#pragma unroll
  for (int n = 0; n < 4; ++n) bro[n] = (wc * 64 + n * 16 + (lane & 15)) * 64 + rdsw;

  f32x4 acc[8][4];
#pragma unroll
  for (int m = 0; m < 8; ++m)
#pragma unroll
    for (int n = 0; n < 4; ++n) acc[m][n] = (f32x4){0.f, 0.f, 0.f, 0.f};

  auto stage = [&](int s) {
    const int tap = s >> 4;
    const int ci0 = (s & 15) << 5;
    const int kh = tap / 3;
    const int kw = tap - kh * 3;
    const int q = s & 3;
    const ushort* Wb = Wt + tap * 262144 + ci0;
    const ushort* Xb = xs + (kh * 66 + kw) * 512 + ci0;
    async_copy16(Wb + aoff[0], ldsA[0] + q * 8192);
    async_copy16(Wb + aoff[1], ldsA[1] + q * 8192);
    async_copy16(Xb + boff[0], ldsB[0] + q * 8192);
    async_copy16(Xb + boff[1], ldsB[1] + q * 8192);
  };

  // double fragment banks (full-slice lookahead)
  bf16x8 afA[8], bvA[4], afB[8], bvB[4];

  // prologue: stage ring slots 0..2; prime bank A with slice 0
  stage(0);
  stage(1);
  stage(2);
  WAITVM(8);
  __builtin_amdgcn_s_barrier();
  READS(0, afA, bvA);

  // main: 144 phases; phase p MFMAs slice p, reads slice p+1
  for (int s = 0; s < 140; s += 2) {
    PH(s, 4, true, true, afB, bvB, afA, bvA);
    PH(s + 1, 4, true, true, afA, bvA, afB, bvB);
  }
  PH(140, 4, true, true, afB, bvB, afA, bvA);   // stages slice 143
  PH(141, 4, true, false, afA, bvA, afB, bvB);
  PH(142, 0, true, false, afB, bvB, afA, bvA);
  PH(143, 0, false, false, afA, bvA, afB, bvB);

  // epilogue
  const float sn = scale_noise[0];
  const int colp = lane & 15;
  const int rq = (lane >> 4) * 4;
  float nz[4];
#pragma unroll
  for (int n = 0; n < 4; ++n)
    nz[n] = sn * noise[b * 4096 + px0 + wc * 64 + n * 16 + colp];
#pragma unroll
  for (int m = 0; m < 8; ++m) {
    const int cob = co0 + wr * 128 + m * 16 + rq;
    float sg[4], bs[4], am[4];
#pragma unroll
    for (int r = 0; r < 4; ++r) {
      sg[r] = sig[b * 512 + cob + r];
      bs[r] = bias[cob + r];
      am[r] = (OUT_MODE == 0) ? amod[b * 512 + cob + r] : 0.f;
    }
#pragma unroll
    for (int n = 0; n < 4; ++n) {
      const int px = px0 + wc * 64 + n * 16 + colp;
      if (OUT_MODE == 0) {
        const int hh = px >> 6, ww = px & 63;
        ushort pk[4];
#pragma unroll
        for (int r = 0; r < 4; ++r) {
          float v = acc[m][n][r] * sg[r] + nz[n] + bs[r];
          v = (v > 0.f) ? v : 0.2f * v;
          pk[r] = f2bf(v * am[r]);
        }
        uint2 u;
        u.x = (uint32_t)pk[0] | ((uint32_t)pk[1] << 16);
        u.y = (uint32_t)pk[2] | ((uint32_t)pk[3] << 16);
        *(uint2*)((ushort*)outp + (((size_t)b * 66 + hh + 1) * 66 + (ww + 1)) * 512 + cob) = u;
      } else {
#pragma unroll
        for (int r = 0; r < 4; ++r) {
          float v = acc[m][n][r] * sg[r] + nz[n] + bs[r];
          v = (v > 0.f) ? v : 0.2f * v;
          ((float*)outp)[((size_t)b * 512 + cob + r) * 4096 + px] = v;
        }
      }
    }
  }
}

// ---------------- RGB 1x1 conv (no demod)
__global__ void rgb_k(const float* __restrict__ X, const float* __restrict__ Ar,
                      const float* __restrict__ rgbW, const float* __restrict__ rgbB,
                      float* __restrict__ out) {
  __shared__ float wmod[3 * 512];
  const int b = blockIdx.y;
  const int tid = threadIdx.x;
  const float c = 0.04419417382415922f;  // 1/sqrt(512)
  for (int idx = tid; idx < 1536; idx += 256)
    wmod[idx] = rgbW[idx] * c * Ar[b * 512 + (idx & 511)];
  __syncthreads();
  const int p = blockIdx.x * 256 + tid;
  const float* xb = X + (size_t)b * 512 * 4096 + p;
  float a0 = 0.f, a1 = 0.f, a2 = 0.f;
  for (int ci = 0; ci < 512; ++ci) {
    float xv = xb[(size_t)ci * 4096];
    a0 += wmod[ci] * xv;
    a1 += wmod[512 + ci] * xv;
    a2 += wmod[1024 + ci] * xv;
  }
  float v0 = a0 + rgbB[0], v1 = a1 + rgbB[1], v2 = a2 + rgbB[2];
  v0 = (v0 > 0.f) ? v0 : 0.2f * v0;
  v1 = (v1 > 0.f) ? v1 : 0.2f * v1;
  v2 = (v2 > 0.f) ? v2 : 0.2f * v2;
  out[((size_t)b * 3 + 0) * 4096 + p] = v0;
  out[((size_t)b * 3 + 1) * 4096 + p] = v1;
  out[((size_t)b * 3 + 2) * 4096 + p] = v2;
}

extern "C" void kernel_launch(void* const* d_in, const int* in_sizes, int n_in,
                              void* d_out, int out_size, void* d_ws, size_t ws_size,
                              hipStream_t stream) {
  const float* x     = (const float*)d_in[0];
  const float* w     = (const float*)d_in[1];
  const float* noise = (const float*)d_in[2];
  const float* s1_sW = (const float*)d_in[3];
  const float* s1_sb = (const float*)d_in[4];
  const float* s1_cW = (const float*)d_in[5];
  const float* s1_sn = (const float*)d_in[6];
  const float* s1_b  = (const float*)d_in[7];
  const float* s2_sW = (const float*)d_in[8];
  const float* s2_sb = (const float*)d_in[9];
  const float* s2_cW = (const float*)d_in[10];
  const float* s2_sn = (const float*)d_in[11];
  const float* s2_b  = (const float*)d_in[12];
  const float* r_sW  = (const float*)d_in[13];
  const float* r_sb  = (const float*)d_in[14];
  const float* r_cW  = (const float*)d_in[15];
  const float* r_b   = (const float*)d_in[16];

  char* ws = (char*)d_ws;
  float*  A1  = (float*)(ws + 0);
  float*  A2  = (float*)(ws + 16384);
  float*  Arr = (float*)(ws + 32768);
  float*  sg1 = (float*)(ws + 49152);
  float*  sg2 = (float*)(ws + 65536);
  ushort* Wt1 = (ushort*)(ws + 98304);            // 4.5 MB
  ushort* xs1 = (ushort*)(ws + 4816896);          // padded NHWC, 35.7 MB
  ushort* Wt2 = (ushort*)(ws + 4816896);          // aliases xs1 (used after conv1)
  ushort* xs2 = (ushort*)(ws + 40501248);         // padded NHWC, 35.7 MB
  float* outx   = (float*)d_out;
  float* outrgb = outx + (size_t)8 * 512 * 4096;

  style_linear<<<dim3(128, 8), 256, 0, stream>>>(w, s1_sW, s1_sb, A1);
  style_linear<<<dim3(128, 8), 256, 0, stream>>>(w, s2_sW, s2_sb, A2);
  style_linear<<<dim3(128, 8), 256, 0, stream>>>(w, r_sW, r_sb, Arr);

  prep_sigma<<<512, 512, 0, stream>>>(s1_cW, A1, Wt1, sg1);

  zero_border<<<1040, 256, 0, stream>>>((uint4*)xs1, (uint4*)xs2);
  mod_transpose<<<dim3(64, 4, 8), 256, 0, stream>>>(x, A1, xs1);

  conv3x3<0><<<dim3(256), 512, 0, stream>>>(xs1, Wt1, sg1, noise, s1_sn, s1_b, A2, (void*)xs2);
  prep_sigma<<<512, 512, 0, stream>>>(s2_cW, A2, Wt2, sg2);  // Wt2 aliases xs1: after conv1
  conv3x3<1><<<dim3(256), 512, 0, stream>>>(xs2, Wt2, sg2, noise + 32768, s2_sn, s2_b, sg2,
                                            (void*)outx);
  rgb_k<<<dim3(16, 8), 256, 0, stream>>>(outx, Arr, r_cW, r_b, outrgb);
}